// Round 14
// baseline (353.424 us; speedup 1.0000x reference)
//
#include <hip/hip_runtime.h>
#include <hip/hip_bf16.h>

#define FEAT    512
#define HEADS   4
#define NEG     0.2f

typedef unsigned int uint;
typedef unsigned short ushort_t;
typedef __attribute__((ext_vector_type(8))) short bf16x8v;   // 8 bf16 = 4 VGPRs
typedef __attribute__((ext_vector_type(4))) float f32x4v;    // mfma acc
typedef __attribute__((address_space(3))) uint lds_u32_t;
typedef __attribute__((address_space(1))) const uint g_u32_t;

__device__ inline float bf2f(ushort_t h) { return __uint_as_float(((uint)h) << 16); }
__device__ inline ushort_t f2bf(float f) {
    uint u = __float_as_uint(f);
    u += 0x7fff + ((u >> 16) & 1);           // RNE
    return (ushort_t)(u >> 16);
}
__device__ inline float2 up2(uint d) {       // 2 packed bf16 -> float2, 2 inst
    return make_float2(__uint_as_float(d << 16), __uint_as_float(d & 0xffff0000u));
}
__device__ inline float2 f2add(float2 a, float2 b) { return make_float2(a.x + b.x, a.y + b.y); }
__device__ inline float2 f2min0(float2 a) { return make_float2(fminf(a.x, 0.f), fminf(a.y, 0.f)); }
__device__ inline float2 f2fma(float2 a, float2 b, float2 c) {
    return make_float2(fmaf(a.x, b.x, c.x), fmaf(a.y, b.y, c.y));
}
__device__ inline float2 f2fmas(float s, float2 b, float2 c) {
    return make_float2(fmaf(s, b.x, c.x), fmaf(s, b.y, c.y));
}

// ---------------------------------------------------------------------------
// dtype probe (wave-parallel): flag=1 -> input stored as bf16
// ---------------------------------------------------------------------------
__global__ void probe_dtype(const ushort_t* __restrict__ x, int* flag) {
    int lane = threadIdx.x;   // 64 threads
    int hits = 0;
    for (int i = lane; i < 128; i += 64) {
        ushort_t w = x[2 * i];
        uint hb = (w >> 8) & 0x7f;
        hits += (hb >= 0x38 && hb <= 0x42) ? 1 : 0;
    }
    #pragma unroll
    for (int off = 32; off >= 1; off >>= 1) hits += __shfl_xor(hits, off);
    if (lane == 0) *flag = (hits >= 64) ? 1 : 0;
}

// canonicalize float array (bf16 or fp32 storage) into bf16.
__global__ __launch_bounds__(256) void canon_kernel(const void* __restrict__ in,
                                                    ushort_t* __restrict__ outp,
                                                    const int* __restrict__ flag, long long n,
                                                    int skip_if_bf16) {
    int isbf = *flag;
    if (isbf && skip_if_bf16) return;
    long long i0 = ((long long)blockIdx.x * 256 + threadIdx.x) * 8;
    if (i0 + 8 <= n) {
        if (isbf) {
            *(uint4*)&outp[i0] = *(const uint4*)((const ushort_t*)in + i0);
        } else {
            const float* f = (const float*)in + i0;
            float4 a = *(const float4*)f, b = *(const float4*)(f + 4);
            ushort_t o[8] = {f2bf(a.x), f2bf(a.y), f2bf(a.z), f2bf(a.w),
                             f2bf(b.x), f2bf(b.y), f2bf(b.z), f2bf(b.w)};
            *(uint4*)&outp[i0] = *(uint4*)o;
        }
    } else {
        for (long long i = i0; i < n; ++i)
            outp[i] = isbf ? ((const ushort_t*)in)[i] : f2bf(((const float*)in)[i]);
    }
}

// fused canon of the 4 small arrays (att, bias, Wc, bc) in one dispatch
__global__ __launch_bounds__(256) void canon_small4(
    const void* a0, ushort_t* o0, int n0, const void* a1, ushort_t* o1, int n1,
    const void* a2, ushort_t* o2, int n2, const void* a3, ushort_t* o3, int n3,
    const int* __restrict__ flag) {
    int isbf = *flag;
    int idx = blockIdx.x * 256 + threadIdx.x;
    const void* srcs[4] = {a0, a1, a2, a3};
    ushort_t* dsts[4] = {o0, o1, o2, o3};
    int ns[4] = {n0, n1, n2, n3};
    #pragma unroll
    for (int k = 0; k < 4; ++k) {
        if (idx < ns[k]) {
            dsts[k][idx] = isbf ? ((const ushort_t*)srcs[k])[idx]
                                : f2bf(((const float*)srcs[k])[idx]);
            return;
        }
        idx -= ns[k];
    }
}

// ---------------------------------------------------------------------------
// CSR build by dst (deg zeroed via hipMemsetAsync; self-loop folded into scan)
// ---------------------------------------------------------------------------
__global__ void hist_kernel(const int* __restrict__ dst, int* deg, int E, int N) {
    int i = blockIdx.x * blockDim.x + threadIdx.x;
    if (i < E) {
        int d = dst[i];
        if ((uint)d < (uint)N) atomicAdd(&deg[d], 1);
    }
}

// phase 1: per-1024-block exclusive scan over (deg[i] + 1)  [+1 = self-loop]
__global__ __launch_bounds__(256) void scan1(const int* __restrict__ deg, int* __restrict__ part,
                                             int* __restrict__ bsum, int N) {
    __shared__ int tmp[256];
    int b = blockIdx.x, tid = threadIdx.x;
    int i0 = b * 1024 + tid * 4;
    int v[4] = {0, 0, 0, 0};
    if (i0 + 4 <= N) { int4 q = *(const int4*)&deg[i0]; v[0]=q.x+1; v[1]=q.y+1; v[2]=q.z+1; v[3]=q.w+1; }
    else { for (int j = 0; j < 4; ++j) v[j] = (i0 + j < N) ? deg[i0 + j] + 1 : 0; }
    int s0 = v[0], s1 = s0 + v[1], s2 = s1 + v[2], s3 = s2 + v[3];
    tmp[tid] = s3;
    __syncthreads();
    for (int off = 1; off < 256; off <<= 1) {
        int t = (tid >= off) ? tmp[tid - off] : 0;
        __syncthreads();
        tmp[tid] += t;
        __syncthreads();
    }
    int base = tid ? tmp[tid - 1] : 0;
    int e[4] = {base, base + s0, base + s1, base + s2};
    if (i0 + 4 <= N) { *(int4*)&part[i0] = make_int4(e[0], e[1], e[2], e[3]); }
    else { for (int j = 0; j < 4; ++j) if (i0 + j < N) part[i0 + j] = e[j]; }
    if (tid == 255) bsum[b] = tmp[255];
}

// phase 2 (fused): each block wave-scans the Nb block sums itself (Nb <= 64)
__global__ __launch_bounds__(256) void scan3(const int* __restrict__ part, const int* __restrict__ bsum,
                                             int* __restrict__ offsets, int* __restrict__ cursor,
                                             int N, int Nb) {
    __shared__ int s_add, s_tot;
    int b = blockIdx.x, tid = threadIdx.x;
    if (tid < 64) {
        int v = (tid < Nb) ? bsum[tid] : 0;
        int incl = v;
        #pragma unroll
        for (int off = 1; off < 64; off <<= 1) {
            int t = __shfl_up(incl, off);
            if (tid >= off) incl += t;
        }
        if (tid == b) s_add = incl - v;
        if (tid == Nb - 1) s_tot = incl;
    }
    __syncthreads();
    int add = s_add;
    int i0 = b * 1024 + tid * 4;
    #pragma unroll
    for (int j = 0; j < 4; ++j) {
        int i = i0 + j;
        if (i < N) { int o = part[i] + add; offsets[i] = o; cursor[i] = o; }
    }
    if (b == Nb - 1 && tid == 0) offsets[N] = s_tot;   // = E + N
}

__global__ void scatter_kernel(const int* __restrict__ src, const int* __restrict__ dst,
                               int* cursor, int* srcs, int E, int N) {
    int i = blockIdx.x * blockDim.x + threadIdx.x;
    if (i >= E + N) return;
    int s, d;
    if (i < E) { s = src[i]; d = dst[i]; }
    else       { s = i - E; d = i - E; }   // self-loop
    if ((uint)d >= (uint)N) return;
    int pos = atomicAdd(&cursor[d], 1);
    if ((uint)pos < (uint)(E + N)) srcs[pos] = s;
}

// ---------------------------------------------------------------------------
// dual-dtype transpose+canon for BOTH weight matrices in one dispatch (z = 0/1)
// out[N][K] (bf16) = in[K][N] (bf16 or fp32)
// ---------------------------------------------------------------------------
__global__ __launch_bounds__(256) void transpose_canon2(const void* __restrict__ inL,
                                                        const void* __restrict__ inR,
                                                        ushort_t* __restrict__ outL,
                                                        ushort_t* __restrict__ outR,
                                                        const int* __restrict__ flag,
                                                        int K, int N) {
    __shared__ ushort_t t[64][72];
    const void* in = blockIdx.z ? inR : inL;
    ushort_t* outp = blockIdx.z ? outR : outL;
    int k0 = blockIdx.y * 64, n0 = blockIdx.x * 64;
    int tid = threadIdx.x;
    int r = tid >> 3;            // 0..31
    int c = (tid & 7) * 8;       // 0,8,..,56
    int isbf = *flag;
    #pragma unroll
    for (int p = 0; p < 2; ++p) {
        int row = r + p * 32;
        size_t base = (size_t)(k0 + row) * N + n0 + c;
        if (isbf) {
            *(uint4*)&t[row][c] = *(const uint4*)((const ushort_t*)in + base);
        } else {
            const float* f = (const float*)in + base;
            float4 a = *(const float4*)f, b = *(const float4*)(f + 4);
            ushort_t o[8] = {f2bf(a.x), f2bf(a.y), f2bf(a.z), f2bf(a.w),
                             f2bf(b.x), f2bf(b.y), f2bf(b.z), f2bf(b.w)};
            *(uint4*)&t[row][c] = *(uint4*)o;
        }
    }
    __syncthreads();
    #pragma unroll
    for (int p = 0; p < 2; ++p) {
        int row = r + p * 32;
        #pragma unroll
        for (int j = 0; j < 8; ++j)
            outp[(size_t)(n0 + row) * K + k0 + c + j] = t[c + j][row];
    }
}

// ---------------------------------------------------------------------------
// MFMA bf16 GEMM: C[M,N] = A[M,K] @ Bt[N,K]^T. 128x128 tile, 4 waves of 64x64.
// BK=64 via two k-panels per staging iter (r10 structure, 118.5 us measured).
// Grid: blockIdx.x = COL tile (r10 order; r12's row-fast re-streamed A 32x).
// Epilogue: C tile bounced through LDS (stride 132) -> 16B coalesced stores
// (was 64 scalar 2B stores/thread).
// ---------------------------------------------------------------------------
__global__ __launch_bounds__(256) void gemm128(const ushort_t* A_bf, const ushort_t* A_cv,
                                               const int* __restrict__ flag,
                                               const ushort_t* __restrict__ Bt,
                                               ushort_t* __restrict__ C,
                                               int M, int Nn, int K) {
    constexpr int CSTR = 132;                 // epilogue row stride (bank spread)
    __shared__ ushort_t SH[128 * CSTR];       // 33792 B; staging uses first 32KB
    ushort_t* As = SH;                        // As[2][4096]
    ushort_t* Bs = SH + 8192;                 // Bs[2][4096]
    const ushort_t* A = (*flag) ? A_bf : A_cv;
    int tid = threadIdx.x;
    int wave = tid >> 6, lane = tid & 63;
    int row0 = blockIdx.y * 128, col0 = blockIdx.x * 128;
    int wm = (wave >> 1) * 64, wn = (wave & 1) * 64;

    f32x4v acc[4][4];
    #pragma unroll
    for (int i = 0; i < 4; ++i)
        #pragma unroll
        for (int j = 0; j < 4; ++j) acc[i][j] = (f32x4v){0.f, 0.f, 0.f, 0.f};

    int fm = lane & 15, kq8 = (lane >> 4) * 8;

    // staging (r6 mapping, coalesced 64B runs): chunk p -> row=p>>2, kp=p&3
    const ushort_t* srcA[2]; ushort_t* dstA0[2]; ushort_t* dstA1[2];
    const ushort_t* srcB[2]; ushort_t* dstB0[2]; ushort_t* dstB1[2];
    #pragma unroll
    for (int i = 0; i < 2; ++i) {
        int p = (wave * 2 + i) * 64 + lane;
        int row = p >> 2, kp = p & 3;
        int gra = row0 + row; if (gra >= M) gra = M - 1;   // tail clamp (C-write guarded)
        srcA[i] = &A[(size_t)gra * K + kp * 8];
        srcB[i] = &Bt[(size_t)(col0 + row) * K + kp * 8];
        dstA0[i] = &As[p * 8]; dstA1[i] = &As[4096 + p * 8];
        dstB0[i] = &Bs[p * 8]; dstB1[i] = &Bs[4096 + p * 8];
    }

    for (int k0 = 0; k0 < K; k0 += 64) {
        #pragma unroll
        for (int i = 0; i < 2; ++i) {
            __builtin_amdgcn_global_load_lds((g_u32_t*)srcA[i],        (lds_u32_t*)dstA0[i], 16, 0, 0);
            __builtin_amdgcn_global_load_lds((g_u32_t*)(srcA[i] + 32), (lds_u32_t*)dstA1[i], 16, 0, 0);
            __builtin_amdgcn_global_load_lds((g_u32_t*)srcB[i],        (lds_u32_t*)dstB0[i], 16, 0, 0);
            __builtin_amdgcn_global_load_lds((g_u32_t*)(srcB[i] + 32), (lds_u32_t*)dstB1[i], 16, 0, 0);
            srcA[i] += 64; srcB[i] += 64;
        }
        __syncthreads();

        #pragma unroll
        for (int panel = 0; panel < 2; ++panel) {
            bf16x8v af[4], bfr[4];
            #pragma unroll
            for (int mi = 0; mi < 4; ++mi)
                af[mi] = *(const bf16x8v*)&As[panel * 4096 + (wm + mi * 16 + fm) * 32 + kq8];
            #pragma unroll
            for (int nj = 0; nj < 4; ++nj)
                bfr[nj] = *(const bf16x8v*)&Bs[panel * 4096 + (wn + nj * 16 + fm) * 32 + kq8];
            #pragma unroll
            for (int mi = 0; mi < 4; ++mi)
                #pragma unroll
                for (int nj = 0; nj < 4; ++nj)
                    acc[mi][nj] = __builtin_amdgcn_mfma_f32_16x16x32_bf16(af[mi], bfr[nj], acc[mi][nj], 0, 0, 0);
        }
        __syncthreads();
    }

    // epilogue: C/D layout col = lane&15, row = (lane>>4)*4 + r  [verified r4-r13]
    // -> LDS (stride 132), then 16B coalesced global stores
    int col = lane & 15, rq = (lane >> 4) * 4;
    #pragma unroll
    for (int mi = 0; mi < 4; ++mi)
        #pragma unroll
        for (int r = 0; r < 4; ++r)
            #pragma unroll
            for (int nj = 0; nj < 4; ++nj)
                SH[(wm + mi * 16 + rq + r) * CSTR + wn + nj * 16 + col] = f2bf(acc[mi][nj][r]);
    __syncthreads();
    #pragma unroll
    for (int j = 0; j < 8; ++j) {
        int base = (tid + j * 256) * 8;        // idx in 128x128 space
        int r = base >> 7, c = base & 127;
        int gm = row0 + r;
        if (gm < M)
            *(uint4*)&C[(size_t)gm * Nn + col0 + c] = *(const uint4*)&SH[r * CSTR + c];
    }
}

// ---------------------------------------------------------------------------
// Fused edge/softmax/aggregate/mean-heads/bias/classifier. No running-max
// (scores bounded << 88, exp safe in f32). OUTPUT FP32.
// Block = dst node; wave h = head h; lane owns channels c = lane*8+j.
// 3-slot pipeline; per-lane BYTE offsets precomputed (one mul per 64 edges).
// ---------------------------------------------------------------------------
__global__ __launch_bounds__(256) void gat_aggregate(
    const ushort_t* __restrict__ xl, int xl_stride,
    const ushort_t* __restrict__ xr, int xr_stride,
    const int* __restrict__ offsets, const int* __restrict__ srcs,
    const ushort_t* __restrict__ att, const ushort_t* __restrict__ bias,
    const ushort_t* __restrict__ Wc, const ushort_t* __restrict__ bc,
    float* __restrict__ out, int c0, int Cn, int N, int EN) {
    int bn = blockIdx.x;
    if (bn >= Cn) return;
    int n = c0 + bn;
    int tid = threadIdx.x;
    int h = tid >> 6, lane = tid & 63;
    int hoff = h * FEAT + lane * 8;

    __shared__ float sh[HEADS][FEAT];
    __shared__ float r0s[HEADS], r1s[HEADS];

    float2 xrr[4], attr[4];
    { uint4 q = *(const uint4*)&xr[(size_t)bn * xr_stride + hoff];
      xrr[0] = up2(q.x); xrr[1] = up2(q.y); xrr[2] = up2(q.z); xrr[3] = up2(q.w); }
    { uint4 q = *(const uint4*)&att[hoff];
      attr[0] = up2(q.x); attr[1] = up2(q.y); attr[2] = up2(q.z); attr[3] = up2(q.w); }

    int start = offsets[n], end = offsets[n + 1];
    start = max(0, min(start, EN));
    end   = max(start, min(end, EN));
    int deg = end - start;

    uint stride_b = (uint)xl_stride * 2u;
    uint ov = 0;
    if (lane < deg) {
        int s = srcs[start + lane];
        if ((uint)s < (uint)N) ov = (uint)s * stride_b;
    }

    float l = 0.f;
    float2 acc[4] = {{0.f,0.f},{0.f,0.f},{0.f,0.f},{0.f,0.f}};
    const char* xlb = (const char*)(xl + hoff);
    const float2 cneg = make_float2(NEG - 1.0f, NEG - 1.0f);

    auto getO = [&](int i) -> uint {
        if (i >= deg) i = deg - 1;
        if (i < 0) i = 0;
        if (i < 64) return (uint)__shfl((int)ov, i);
        int s = srcs[start + i];
        if ((uint)s >= (uint)N) s = 0;
        return (uint)s * stride_b;
    };
    auto fetchPair = [&](int i0, uint4& q0, uint4& q1) {
        uint o0 = getO(i0), o1 = getO(i0 + 1);
        q0 = *(const uint4*)(xlb + o0);
        q1 = *(const uint4*)(xlb + o1);
    };
    auto body = [&](uint4 q) {
        float2 v[4] = {up2(q.x), up2(q.y), up2(q.z), up2(q.w)};
        float2 p2 = make_float2(0.f, 0.f);
        #pragma unroll
        for (int j = 0; j < 4; ++j) {
            float2 u  = f2add(v[j], xrr[j]);
            float2 lr = f2fma(f2min0(u), cneg, u);   // 2-op LeakyReLU (packed)
            p2 = f2fma(lr, attr[j], p2);
        }
        float p = p2.x + p2.y;
        #pragma unroll
        for (int off = 32; off >= 1; off >>= 1) p += __shfl_xor(p, off);
        float w = __expf(p);
        l += w;
        #pragma unroll
        for (int j = 0; j < 4; ++j) acc[j] = f2fmas(w, v[j], acc[j]);
    };

    uint4 a0, a1, b0, b1, q0, q1;
    fetchPair(0, a0, a1);
    fetchPair(2, b0, b1);
    for (int e = 0; e < deg; e += 2) {
        fetchPair(e + 4, q0, q1);    // clamped on tail -> L1 hit, discarded
        body(a0);
        if (e + 1 < deg) body(a1);
        a0 = b0; a1 = b1; b0 = q0; b1 = q1;
    }

    float inv = 0.25f / fmaxf(l, 1e-35f);   // 1/l, mean over heads folded in
    #pragma unroll
    for (int j = 0; j < 4; ++j) {
        sh[h][lane * 8 + 2 * j]     = acc[j].x * inv;
        sh[h][lane * 8 + 2 * j + 1] = acc[j].y * inv;
    }
    __syncthreads();

    float p0 = 0.f, p1 = 0.f;
    for (int c = tid; c < FEAT; c += 256) {
        float f = sh[0][c] + sh[1][c] + sh[2][c] + sh[3][c] + bf2f(bias[c]);
        uint w2 = *(const uint*)&Wc[c * 2];
        p0 = fmaf(f, bf2f((ushort_t)(w2 & 0xffff)), p0);
        p1 = fmaf(f, bf2f((ushort_t)(w2 >> 16)), p1);
    }
    #pragma unroll
    for (int off = 32; off >= 1; off >>= 1) {
        p0 += __shfl_xor(p0, off);
        p1 += __shfl_xor(p1, off);
    }
    if (lane == 0) { r0s[h] = p0; r1s[h] = p1; }
    __syncthreads();
    if (tid == 0) {
        out[(size_t)n * 2 + 0] = r0s[0] + r0s[1] + r0s[2] + r0s[3] + bf2f(bc[0]);
        out[(size_t)n * 2 + 1] = r1s[0] + r1s[1] + r1s[2] + r1s[3] + bf2f(bc[1]);
    }
}

// ---------------------------------------------------------------------------
extern "C" void kernel_launch(void* const* d_in, const int* in_sizes, int n_in,
                              void* d_out, int out_size, void* d_ws, size_t ws_size,
                              hipStream_t stream) {
    const void* x    = d_in[0];
    const int*  ei   = (const int*)d_in[1];
    const void* W_l  = d_in[2];
    const void* W_r  = d_in[3];
    const void* att  = d_in[4];
    const void* bias = d_in[5];
    const void* Wc   = d_in[6];
    const void* bc   = d_in[7];
    float* out = (float*)d_out;

    const int N  = in_sizes[0] / FEAT;     // 20000
    const int E  = in_sizes[1] / 2;        // 160000
    const int K  = FEAT;                   // 512
    const int HC = HEADS * FEAT;           // 2048
    const int EN = E + N;
    const int Nb = (N + 1023) / 1024;      // scan blocks (20 <= 64)

    const int* src = ei;
    const int* dst = ei + E;

    // ---- adaptive workspace layout ----
    char* base = (char*)d_ws;
    size_t off = 0;
    auto alloc = [&](size_t bytes) -> char* {
        char* p = base + off;
        off = (off + bytes + 255) & ~(size_t)255;
        return p;
    };
    int* flag    = (int*)alloc(4);
    int* offsets = (int*)alloc((size_t)(N + 1) * 4);
    int* cursor  = (int*)alloc((size_t)N * 4);
    int* deg     = (int*)alloc((size_t)N * 4);
    int* part    = (int*)alloc((size_t)N * 4);
    int* bsum    = (int*)alloc((size_t)(Nb + 1) * 4);
    int* srcs    = (int*)alloc((size_t)EN * 4);
    ushort_t* attc  = (ushort_t*)alloc((size_t)HC * 2);
    ushort_t* biasc = (ushort_t*)alloc((size_t)FEAT * 2);
    ushort_t* Wcc   = (ushort_t*)alloc((size_t)FEAT * 2 * 2);
    ushort_t* bcc   = (ushort_t*)alloc(2 * 2);
    ushort_t* xc   = (ushort_t*)alloc((size_t)N * K * 2);
    ushort_t* Wcat = (ushort_t*)alloc((size_t)2 * HC * K * 2);   // [Wl^T ; Wr^T]
    size_t fixed = off;

    size_t need_merged = (size_t)N * 2 * HC * 2;
    bool merged = (ws_size >= fixed + need_merged);

    // 0) dtype probe + canonicalize (x canon skipped when bf16; small inputs fused)
    probe_dtype<<<1, 64, 0, stream>>>((const ushort_t*)x, flag);
    long long NX = (long long)N * K;
    canon_kernel<<<(int)((NX + 2047) / 2048), 256, 0, stream>>>(x, xc, flag, NX, 1);
    canon_small4<<<15, 256, 0, stream>>>(att, attc, HC, bias, biasc, FEAT,
                                         Wc, Wcc, FEAT * 2, bc, bcc, 2, flag);

    // 1) CSR build (memset deg; +1 self-loop folded into scan1; scan2 fused into scan3)
    hipMemsetAsync(deg, 0, (size_t)N * 4, stream);
    hist_kernel<<<(E + 255) / 256, 256, 0, stream>>>(dst, deg, E, N);
    scan1<<<Nb, 256, 0, stream>>>(deg, part, bsum, N);
    scan3<<<Nb, 256, 0, stream>>>(part, bsum, offsets, cursor, N, Nb);
    scatter_kernel<<<(EN + 255) / 256, 256, 0, stream>>>(src, dst, cursor, srcs, E, N);

    // 2) transpose+canon both weights in one dispatch
    dim3 tg(HC / 64, K / 64, 2);
    transpose_canon2<<<tg, 256, 0, stream>>>(W_l, W_r, Wcat, Wcat + (size_t)HC * K,
                                             flag, K, HC);

    const ushort_t* x_bf = (const ushort_t*)x;

    if (merged) {
        ushort_t* xlr = (ushort_t*)(base + fixed);       // N x 4096: [xl | xr]
        dim3 gg(2 * HC / 128, (N + 127) / 128);          // x = col tiles (r10 order)
        gemm128<<<gg, 256, 0, stream>>>(x_bf, xc, flag, Wcat, xlr, N, 2 * HC, K);
        gat_aggregate<<<N, 256, 0, stream>>>(xlr, 2 * HC, xlr + HC, 2 * HC,
                                             offsets, srcs, attc, biasc, Wcc, bcc,
                                             out, 0, N, N, EN);
    } else {
        // fallback: separate xl + chunked xr
        ushort_t* xl = (ushort_t*)alloc((size_t)N * HC * 2);
        size_t remain = (ws_size > off) ? (ws_size - off) : 0;
        long long Cmax = (long long)(remain / ((size_t)HC * 2));
        int C = (Cmax >= N) ? N : (int)(Cmax & ~63LL);
        if (C < 64) C = 64;
        ushort_t* xrc = (ushort_t*)(base + off);
        ushort_t* Wlt = Wcat;
        ushort_t* Wrt = Wcat + (size_t)HC * K;

        dim3 gl(HC / 128, (N + 127) / 128);
        gemm128<<<gl, 256, 0, stream>>>(x_bf, xc, flag, Wlt, xl, N, HC, K);
        for (int c0 = 0; c0 < N; c0 += C) {
            int Cn = (N - c0 < C) ? (N - c0) : C;
            dim3 gr(HC / 128, (Cn + 127) / 128);
            gemm128<<<gr, 256, 0, stream>>>(x_bf + (size_t)c0 * K, xc + (size_t)c0 * K, flag,
                                            Wrt, xrc, Cn, HC, K);
            gat_aggregate<<<Cn, 256, 0, stream>>>(xl, HC, xrc, HC,
                                                  offsets, srcs, attc, biasc, Wcc, bcc,
                                                  out, c0, Cn, N, EN);
        }
    }
}

// Round 15
// 337.438 us; speedup vs baseline: 1.0474x; 1.0474x over previous
//
#include <hip/hip_runtime.h>
#include <hip/hip_bf16.h>

#define FEAT    512
#define HEADS   4
#define NEG     0.2f

typedef unsigned int uint;
typedef unsigned short ushort_t;
typedef __attribute__((ext_vector_type(8))) short bf16x8v;   // 8 bf16 = 4 VGPRs
typedef __attribute__((ext_vector_type(4))) float f32x4v;    // mfma acc
typedef __attribute__((address_space(3))) uint lds_u32_t;
typedef __attribute__((address_space(1))) const uint g_u32_t;

__device__ inline float bf2f(ushort_t h) { return __uint_as_float(((uint)h) << 16); }
__device__ inline ushort_t f2bf(float f) {
    uint u = __float_as_uint(f);
    u += 0x7fff + ((u >> 16) & 1);           // RNE
    return (ushort_t)(u >> 16);
}
__device__ inline float2 up2(uint d) {       // 2 packed bf16 -> float2, 2 inst
    return make_float2(__uint_as_float(d << 16), __uint_as_float(d & 0xffff0000u));
}
__device__ inline float2 f2add(float2 a, float2 b) { return make_float2(a.x + b.x, a.y + b.y); }
__device__ inline float2 f2min0(float2 a) { return make_float2(fminf(a.x, 0.f), fminf(a.y, 0.f)); }
__device__ inline float2 f2fma(float2 a, float2 b, float2 c) {
    return make_float2(fmaf(a.x, b.x, c.x), fmaf(a.y, b.y, c.y));
}
__device__ inline float2 f2fmas(float s, float2 b, float2 c) {
    return make_float2(fmaf(s, b.x, c.x), fmaf(s, b.y, c.y));
}

// ---------------------------------------------------------------------------
// fused prep: dtype probe (per-block, from the same 256B of x -> no cross-block
// dep), deg zeroing, small-array canon, and x canon. 1 dispatch replaces 4.
// block roles: [0,NBZ) zero deg | [NBZ,NBZ+15) canon small4 | rest canon x.
// ---------------------------------------------------------------------------
__global__ __launch_bounds__(256) void prep_kernel(
    const ushort_t* __restrict__ xprobe, int* flag,
    int* __restrict__ deg, int N, int NBZ,
    const void* a0, ushort_t* o0, int n0, const void* a1, ushort_t* o1, int n1,
    const void* a2, ushort_t* o2, int n2, const void* a3, ushort_t* o3, int n3,
    const void* __restrict__ xin, ushort_t* __restrict__ xc, long long nx) {
    __shared__ int s_isbf;
    int tid = threadIdx.x;
    if (tid < 64) {
        int hits = 0;
        for (int i = tid; i < 128; i += 64) {
            ushort_t w = xprobe[2 * i];
            uint hb = (w >> 8) & 0x7f;
            hits += (hb >= 0x38 && hb <= 0x42) ? 1 : 0;
        }
        #pragma unroll
        for (int off = 32; off >= 1; off >>= 1) hits += __shfl_xor(hits, off);
        if (tid == 0) s_isbf = (hits >= 64) ? 1 : 0;
    }
    __syncthreads();
    int isbf = s_isbf;
    int b = blockIdx.x;
    if (b == 0 && tid == 0) *flag = isbf;

    if (b < NBZ) {                       // zero deg (int4)
        int i0 = (b * 256 + tid) * 4;
        if (i0 + 4 <= N) *(int4*)&deg[i0] = make_int4(0, 0, 0, 0);
        else for (int j = 0; j < 4; ++j) if (i0 + j < N) deg[i0 + j] = 0;
        return;
    }
    if (b < NBZ + 15) {                  // canon small4
        int idx = (b - NBZ) * 256 + tid;
        const void* srcs[4] = {a0, a1, a2, a3};
        ushort_t* dsts[4] = {o0, o1, o2, o3};
        int ns[4] = {n0, n1, n2, n3};
        #pragma unroll
        for (int k = 0; k < 4; ++k) {
            if (idx < ns[k]) {
                dsts[k][idx] = isbf ? ((const ushort_t*)srcs[k])[idx]
                                    : f2bf(((const float*)srcs[k])[idx]);
                return;
            }
            idx -= ns[k];
        }
        return;
    }
    if (isbf) return;                    // x used directly when already bf16
    long long i0 = ((long long)(b - NBZ - 15) * 256 + tid) * 8;
    if (i0 + 8 <= nx) {
        const float* f = (const float*)xin + i0;
        float4 a = *(const float4*)f, bb = *(const float4*)(f + 4);
        ushort_t o[8] = {f2bf(a.x), f2bf(a.y), f2bf(a.z), f2bf(a.w),
                         f2bf(bb.x), f2bf(bb.y), f2bf(bb.z), f2bf(bb.w)};
        *(uint4*)&xc[i0] = *(uint4*)o;
    } else {
        for (long long i = i0; i < nx; ++i) xc[i] = f2bf(((const float*)xin)[i]);
    }
}

// ---------------------------------------------------------------------------
// CSR build by dst
// ---------------------------------------------------------------------------
__global__ void hist_kernel(const int* __restrict__ dst, int* deg, int E, int N) {
    int i = blockIdx.x * blockDim.x + threadIdx.x;
    if (i < E) {
        int d = dst[i];
        if ((uint)d < (uint)N) atomicAdd(&deg[d], 1);
    }
}

// phase 1: per-1024-block exclusive scan over (deg[i] + 1)  [+1 = self-loop]
__global__ __launch_bounds__(256) void scan1(const int* __restrict__ deg, int* __restrict__ part,
                                             int* __restrict__ bsum, int N) {
    __shared__ int tmp[256];
    int b = blockIdx.x, tid = threadIdx.x;
    int i0 = b * 1024 + tid * 4;
    int v[4] = {0, 0, 0, 0};
    if (i0 + 4 <= N) { int4 q = *(const int4*)&deg[i0]; v[0]=q.x+1; v[1]=q.y+1; v[2]=q.z+1; v[3]=q.w+1; }
    else { for (int j = 0; j < 4; ++j) v[j] = (i0 + j < N) ? deg[i0 + j] + 1 : 0; }
    int s0 = v[0], s1 = s0 + v[1], s2 = s1 + v[2], s3 = s2 + v[3];
    tmp[tid] = s3;
    __syncthreads();
    for (int off = 1; off < 256; off <<= 1) {
        int t = (tid >= off) ? tmp[tid - off] : 0;
        __syncthreads();
        tmp[tid] += t;
        __syncthreads();
    }
    int base = tid ? tmp[tid - 1] : 0;
    int e[4] = {base, base + s0, base + s1, base + s2};
    if (i0 + 4 <= N) { *(int4*)&part[i0] = make_int4(e[0], e[1], e[2], e[3]); }
    else { for (int j = 0; j < 4; ++j) if (i0 + j < N) part[i0 + j] = e[j]; }
    if (tid == 255) bsum[b] = tmp[255];
}

// phase 2 (fused): each block wave-scans the Nb block sums itself (Nb <= 64)
__global__ __launch_bounds__(256) void scan3(const int* __restrict__ part, const int* __restrict__ bsum,
                                             int* __restrict__ offsets, int* __restrict__ cursor,
                                             int N, int Nb) {
    __shared__ int s_add, s_tot;
    int b = blockIdx.x, tid = threadIdx.x;
    if (tid < 64) {
        int v = (tid < Nb) ? bsum[tid] : 0;
        int incl = v;
        #pragma unroll
        for (int off = 1; off < 64; off <<= 1) {
            int t = __shfl_up(incl, off);
            if (tid >= off) incl += t;
        }
        if (tid == b) s_add = incl - v;
        if (tid == Nb - 1) s_tot = incl;
    }
    __syncthreads();
    int add = s_add;
    int i0 = b * 1024 + tid * 4;
    #pragma unroll
    for (int j = 0; j < 4; ++j) {
        int i = i0 + j;
        if (i < N) { int o = part[i] + add; offsets[i] = o; cursor[i] = o; }
    }
    if (b == Nb - 1 && tid == 0) offsets[N] = s_tot;   // = E + N
}

__global__ void scatter_kernel(const int* __restrict__ src, const int* __restrict__ dst,
                               int* cursor, int* srcs, int E, int N) {
    int i = blockIdx.x * blockDim.x + threadIdx.x;
    if (i >= E + N) return;
    int s, d;
    if (i < E) { s = src[i]; d = dst[i]; }
    else       { s = i - E; d = i - E; }   // self-loop
    if ((uint)d >= (uint)N) return;
    int pos = atomicAdd(&cursor[d], 1);
    if ((uint)pos < (uint)(E + N)) srcs[pos] = s;
}

// ---------------------------------------------------------------------------
// dual-dtype transpose+canon for BOTH weight matrices in one dispatch (z = 0/1)
// out[N][K] (bf16) = in[K][N] (bf16 or fp32)
// ---------------------------------------------------------------------------
__global__ __launch_bounds__(256) void transpose_canon2(const void* __restrict__ inL,
                                                        const void* __restrict__ inR,
                                                        ushort_t* __restrict__ outL,
                                                        ushort_t* __restrict__ outR,
                                                        const int* __restrict__ flag,
                                                        int K, int N) {
    __shared__ ushort_t t[64][72];
    const void* in = blockIdx.z ? inR : inL;
    ushort_t* outp = blockIdx.z ? outR : outL;
    int k0 = blockIdx.y * 64, n0 = blockIdx.x * 64;
    int tid = threadIdx.x;
    int r = tid >> 3;            // 0..31
    int c = (tid & 7) * 8;       // 0,8,..,56
    int isbf = *flag;
    #pragma unroll
    for (int p = 0; p < 2; ++p) {
        int row = r + p * 32;
        size_t base = (size_t)(k0 + row) * N + n0 + c;
        if (isbf) {
            *(uint4*)&t[row][c] = *(const uint4*)((const ushort_t*)in + base);
        } else {
            const float* f = (const float*)in + base;
            float4 a = *(const float4*)f, b = *(const float4*)(f + 4);
            ushort_t o[8] = {f2bf(a.x), f2bf(a.y), f2bf(a.z), f2bf(a.w),
                             f2bf(b.x), f2bf(b.y), f2bf(b.z), f2bf(b.w)};
            *(uint4*)&t[row][c] = *(uint4*)o;
        }
    }
    __syncthreads();
    #pragma unroll
    for (int p = 0; p < 2; ++p) {
        int row = r + p * 32;
        #pragma unroll
        for (int j = 0; j < 8; ++j)
            outp[(size_t)(n0 + row) * K + k0 + c + j] = t[c + j][row];
    }
}

// ---------------------------------------------------------------------------
// MFMA bf16 GEMM: C[M,N] = A[M,K] @ Bt[N,K]^T. 128x128 tile, 4 waves of 64x64.
// BK=64 via two k-panels per staging iter (r10 structure). blockIdx.x = COL
// tile (r10 order; row-fast re-streamed A 32x — measured r12). Epilogue
// bounces C through LDS (stride 132) -> 16B coalesced stores (r14).
// ---------------------------------------------------------------------------
__global__ __launch_bounds__(256) void gemm128(const ushort_t* A_bf, const ushort_t* A_cv,
                                               const int* __restrict__ flag,
                                               const ushort_t* __restrict__ Bt,
                                               ushort_t* __restrict__ C,
                                               int M, int Nn, int K) {
    constexpr int CSTR = 132;                 // epilogue row stride (bank spread)
    __shared__ ushort_t SH[128 * CSTR];       // 33792 B; staging uses first 32KB
    ushort_t* As = SH;                        // As[2][4096]
    ushort_t* Bs = SH + 8192;                 // Bs[2][4096]
    const ushort_t* A = (*flag) ? A_bf : A_cv;
    int tid = threadIdx.x;
    int wave = tid >> 6, lane = tid & 63;
    int row0 = blockIdx.y * 128, col0 = blockIdx.x * 128;
    int wm = (wave >> 1) * 64, wn = (wave & 1) * 64;

    f32x4v acc[4][4];
    #pragma unroll
    for (int i = 0; i < 4; ++i)
        #pragma unroll
        for (int j = 0; j < 4; ++j) acc[i][j] = (f32x4v){0.f, 0.f, 0.f, 0.f};

    int fm = lane & 15, kq8 = (lane >> 4) * 8;

    // staging (r6 mapping, coalesced 64B runs): chunk p -> row=p>>2, kp=p&3
    const ushort_t* srcA[2]; ushort_t* dstA0[2]; ushort_t* dstA1[2];
    const ushort_t* srcB[2]; ushort_t* dstB0[2]; ushort_t* dstB1[2];
    #pragma unroll
    for (int i = 0; i < 2; ++i) {
        int p = (wave * 2 + i) * 64 + lane;
        int row = p >> 2, kp = p & 3;
        int gra = row0 + row; if (gra >= M) gra = M - 1;   // tail clamp (C-write guarded)
        srcA[i] = &A[(size_t)gra * K + kp * 8];
        srcB[i] = &Bt[(size_t)(col0 + row) * K + kp * 8];
        dstA0[i] = &As[p * 8]; dstA1[i] = &As[4096 + p * 8];
        dstB0[i] = &Bs[p * 8]; dstB1[i] = &Bs[4096 + p * 8];
    }

    for (int k0 = 0; k0 < K; k0 += 64) {
        #pragma unroll
        for (int i = 0; i < 2; ++i) {
            __builtin_amdgcn_global_load_lds((g_u32_t*)srcA[i],        (lds_u32_t*)dstA0[i], 16, 0, 0);
            __builtin_amdgcn_global_load_lds((g_u32_t*)(srcA[i] + 32), (lds_u32_t*)dstA1[i], 16, 0, 0);
            __builtin_amdgcn_global_load_lds((g_u32_t*)srcB[i],        (lds_u32_t*)dstB0[i], 16, 0, 0);
            __builtin_amdgcn_global_load_lds((g_u32_t*)(srcB[i] + 32), (lds_u32_t*)dstB1[i], 16, 0, 0);
            srcA[i] += 64; srcB[i] += 64;
        }
        __syncthreads();

        #pragma unroll
        for (int panel = 0; panel < 2; ++panel) {
            bf16x8v af[4], bfr[4];
            #pragma unroll
            for (int mi = 0; mi < 4; ++mi)
                af[mi] = *(const bf16x8v*)&As[panel * 4096 + (wm + mi * 16 + fm) * 32 + kq8];
            #pragma unroll
            for (int nj = 0; nj < 4; ++nj)
                bfr[nj] = *(const bf16x8v*)&Bs[panel * 4096 + (wn + nj * 16 + fm) * 32 + kq8];
            #pragma unroll
            for (int mi = 0; mi < 4; ++mi)
                #pragma unroll
                for (int nj = 0; nj < 4; ++nj)
                    acc[mi][nj] = __builtin_amdgcn_mfma_f32_16x16x32_bf16(af[mi], bfr[nj], acc[mi][nj], 0, 0, 0);
        }
        __syncthreads();
    }

    // epilogue: C/D layout col = lane&15, row = (lane>>4)*4 + r  [verified r4-r14]
    int col = lane & 15, rq = (lane >> 4) * 4;
    #pragma unroll
    for (int mi = 0; mi < 4; ++mi)
        #pragma unroll
        for (int r = 0; r < 4; ++r)
            #pragma unroll
            for (int nj = 0; nj < 4; ++nj)
                SH[(wm + mi * 16 + rq + r) * CSTR + wn + nj * 16 + col] = f2bf(acc[mi][nj][r]);
    __syncthreads();
    #pragma unroll
    for (int j = 0; j < 8; ++j) {
        int base = (tid + j * 256) * 8;        // idx in 128x128 space
        int r = base >> 7, c = base & 127;
        int gm = row0 + r;
        if (gm < M)
            *(uint4*)&C[(size_t)gm * Nn + col0 + c] = *(const uint4*)&SH[r * CSTR + c];
    }
}

// ---------------------------------------------------------------------------
// Fused edge/softmax/aggregate/mean-heads/bias/classifier (r13 version —
// VGPR 40, occupancy 56%; r14's byte-offset variant regressed). OUTPUT FP32.
// Block = dst node; wave h = head h; lane owns channels c = lane*8+j.
// 3-slot pipeline: rows for edges e+4,e+5 prefetched while scoring e,e+1.
// ---------------------------------------------------------------------------
__global__ __launch_bounds__(256) void gat_aggregate(
    const ushort_t* __restrict__ xl, int xl_stride,
    const ushort_t* __restrict__ xr, int xr_stride,
    const int* __restrict__ offsets, const int* __restrict__ srcs,
    const ushort_t* __restrict__ att, const ushort_t* __restrict__ bias,
    const ushort_t* __restrict__ Wc, const ushort_t* __restrict__ bc,
    float* __restrict__ out, int c0, int Cn, int N, int EN) {
    int bn = blockIdx.x;
    if (bn >= Cn) return;
    int n = c0 + bn;
    int tid = threadIdx.x;
    int h = tid >> 6, lane = tid & 63;
    int hoff = h * FEAT + lane * 8;

    __shared__ float sh[HEADS][FEAT];
    __shared__ float r0s[HEADS], r1s[HEADS];

    float2 xrr[4], attr[4];
    { uint4 q = *(const uint4*)&xr[(size_t)bn * xr_stride + hoff];
      xrr[0] = up2(q.x); xrr[1] = up2(q.y); xrr[2] = up2(q.z); xrr[3] = up2(q.w); }
    { uint4 q = *(const uint4*)&att[hoff];
      attr[0] = up2(q.x); attr[1] = up2(q.y); attr[2] = up2(q.z); attr[3] = up2(q.w); }

    int start = offsets[n], end = offsets[n + 1];
    start = max(0, min(start, EN));
    end   = max(start, min(end, EN));
    int deg = end - start;

    int sv = 0;
    if (lane < deg) sv = srcs[start + lane];

    float l = 0.f;
    float2 acc[4] = {{0.f,0.f},{0.f,0.f},{0.f,0.f},{0.f,0.f}};
    const ushort_t* xlh = xl + hoff;
    const float2 cneg = make_float2(NEG - 1.0f, NEG - 1.0f);

    auto getS = [&](int i) -> int {
        if (i >= deg) i = deg - 1;
        if (i < 0) i = 0;
        int s = (i < 64) ? __shfl(sv, i) : srcs[start + i];
        return ((uint)s >= (uint)N) ? 0 : s;
    };
    auto fetchPair = [&](int i0, uint4& q0, uint4& q1) {
        int s0 = getS(i0), s1 = getS(i0 + 1);
        q0 = *(const uint4*)(xlh + (size_t)s0 * xl_stride);
        q1 = *(const uint4*)(xlh + (size_t)s1 * xl_stride);
    };
    auto body = [&](uint4 q) {
        float2 v[4] = {up2(q.x), up2(q.y), up2(q.z), up2(q.w)};
        float2 p2 = make_float2(0.f, 0.f);
        #pragma unroll
        for (int j = 0; j < 4; ++j) {
            float2 u  = f2add(v[j], xrr[j]);
            float2 lr = f2fma(f2min0(u), cneg, u);   // 2-op LeakyReLU (packed)
            p2 = f2fma(lr, attr[j], p2);
        }
        float p = p2.x + p2.y;
        #pragma unroll
        for (int off = 32; off >= 1; off >>= 1) p += __shfl_xor(p, off);
        float w = __expf(p);
        l += w;
        #pragma unroll
        for (int j = 0; j < 4; ++j) acc[j] = f2fmas(w, v[j], acc[j]);
    };

    uint4 a0, a1, b0, b1, q0, q1;
    fetchPair(0, a0, a1);
    fetchPair(2, b0, b1);
    for (int e = 0; e < deg; e += 2) {
        fetchPair(e + 4, q0, q1);    // clamped on tail -> L1 hit, discarded
        body(a0);
        if (e + 1 < deg) body(a1);
        a0 = b0; a1 = b1; b0 = q0; b1 = q1;
    }

    float inv = 0.25f / fmaxf(l, 1e-35f);   // 1/l, mean over heads folded in
    #pragma unroll
    for (int j = 0; j < 4; ++j) {
        sh[h][lane * 8 + 2 * j]     = acc[j].x * inv;
        sh[h][lane * 8 + 2 * j + 1] = acc[j].y * inv;
    }
    __syncthreads();

    float p0 = 0.f, p1 = 0.f;
    for (int c = tid; c < FEAT; c += 256) {
        float f = sh[0][c] + sh[1][c] + sh[2][c] + sh[3][c] + bf2f(bias[c]);
        uint w2 = *(const uint*)&Wc[c * 2];
        p0 = fmaf(f, bf2f((ushort_t)(w2 & 0xffff)), p0);
        p1 = fmaf(f, bf2f((ushort_t)(w2 >> 16)), p1);
    }
    #pragma unroll
    for (int off = 32; off >= 1; off >>= 1) {
        p0 += __shfl_xor(p0, off);
        p1 += __shfl_xor(p1, off);
    }
    if (lane == 0) { r0s[h] = p0; r1s[h] = p1; }
    __syncthreads();
    if (tid == 0) {
        out[(size_t)n * 2 + 0] = r0s[0] + r0s[1] + r0s[2] + r0s[3] + bf2f(bc[0]);
        out[(size_t)n * 2 + 1] = r1s[0] + r1s[1] + r1s[2] + r1s[3] + bf2f(bc[1]);
    }
}

// ---------------------------------------------------------------------------
extern "C" void kernel_launch(void* const* d_in, const int* in_sizes, int n_in,
                              void* d_out, int out_size, void* d_ws, size_t ws_size,
                              hipStream_t stream) {
    const void* x    = d_in[0];
    const int*  ei   = (const int*)d_in[1];
    const void* W_l  = d_in[2];
    const void* W_r  = d_in[3];
    const void* att  = d_in[4];
    const void* bias = d_in[5];
    const void* Wc   = d_in[6];
    const void* bc   = d_in[7];
    float* out = (float*)d_out;

    const int N  = in_sizes[0] / FEAT;     // 20000
    const int E  = in_sizes[1] / 2;        // 160000
    const int K  = FEAT;                   // 512
    const int HC = HEADS * FEAT;           // 2048
    const int EN = E + N;
    const int Nb = (N + 1023) / 1024;      // scan blocks (20 <= 64)

    const int* src = ei;
    const int* dst = ei + E;

    // ---- adaptive workspace layout ----
    char* base = (char*)d_ws;
    size_t off = 0;
    auto alloc = [&](size_t bytes) -> char* {
        char* p = base + off;
        off = (off + bytes + 255) & ~(size_t)255;
        return p;
    };
    int* flag    = (int*)alloc(4);
    int* offsets = (int*)alloc((size_t)(N + 1) * 4);
    int* cursor  = (int*)alloc((size_t)N * 4);
    int* deg     = (int*)alloc((size_t)N * 4);
    int* part    = (int*)alloc((size_t)N * 4);
    int* bsum    = (int*)alloc((size_t)(Nb + 1) * 4);
    int* srcs    = (int*)alloc((size_t)EN * 4);
    ushort_t* attc  = (ushort_t*)alloc((size_t)HC * 2);
    ushort_t* biasc = (ushort_t*)alloc((size_t)FEAT * 2);
    ushort_t* Wcc   = (ushort_t*)alloc((size_t)FEAT * 2 * 2);
    ushort_t* bcc   = (ushort_t*)alloc(2 * 2);
    ushort_t* xc   = (ushort_t*)alloc((size_t)N * K * 2);
    ushort_t* Wcat = (ushort_t*)alloc((size_t)2 * HC * K * 2);   // [Wl^T ; Wr^T]
    size_t fixed = off;

    size_t need_merged = (size_t)N * 2 * HC * 2;
    bool merged = (ws_size >= fixed + need_merged);

    // 0) fused prep: probe + deg-zero + small canon + x canon (1 dispatch)
    long long NX = (long long)N * K;
    const int NBZ = (N + 1023) / 1024;                       // deg-zero blocks
    int nxb = (int)((NX / 8 + 255) / 256);                   // x canon blocks
    prep_kernel<<<NBZ + 15 + nxb, 256, 0, stream>>>(
        (const ushort_t*)x, flag, deg, N, NBZ,
        att, attc, HC, bias, biasc, FEAT, Wc, Wcc, FEAT * 2, bc, bcc, 2,
        x, xc, NX);

    // 1) CSR build
    hist_kernel<<<(E + 255) / 256, 256, 0, stream>>>(dst, deg, E, N);
    scan1<<<Nb, 256, 0, stream>>>(deg, part, bsum, N);
    scan3<<<Nb, 256, 0, stream>>>(part, bsum, offsets, cursor, N, Nb);
    scatter_kernel<<<(EN + 255) / 256, 256, 0, stream>>>(src, dst, cursor, srcs, E, N);

    // 2) transpose+canon both weights in one dispatch
    dim3 tg(HC / 64, K / 64, 2);
    transpose_canon2<<<tg, 256, 0, stream>>>(W_l, W_r, Wcat, Wcat + (size_t)HC * K,
                                             flag, K, HC);

    const ushort_t* x_bf = (const ushort_t*)x;

    if (merged) {
        ushort_t* xlr = (ushort_t*)(base + fixed);       // N x 4096: [xl | xr]
        dim3 gg(2 * HC / 128, (N + 127) / 128);          // x = col tiles (r10 order)
        gemm128<<<gg, 256, 0, stream>>>(x_bf, xc, flag, Wcat, xlr, N, 2 * HC, K);
        gat_aggregate<<<N, 256, 0, stream>>>(xlr, 2 * HC, xlr + HC, 2 * HC,
                                             offsets, srcs, attc, biasc, Wcc, bcc,
                                             out, 0, N, N, EN);
    } else {
        // fallback: separate xl + chunked xr
        ushort_t* xl = (ushort_t*)alloc((size_t)N * HC * 2);
        size_t remain = (ws_size > off) ? (ws_size - off) : 0;
        long long Cmax = (long long)(remain / ((size_t)HC * 2));
        int C = (Cmax >= N) ? N : (int)(Cmax & ~63LL);
        if (C < 64) C = 64;
        ushort_t* xrc = (ushort_t*)(base + off);
        ushort_t* Wlt = Wcat;
        ushort_t* Wrt = Wcat + (size_t)HC * K;

        dim3 gl(HC / 128, (N + 127) / 128);
        gemm128<<<gl, 256, 0, stream>>>(x_bf, xc, flag, Wlt, xl, N, HC, K);
        for (int c0 = 0; c0 < N; c0 += C) {
            int Cn = (N - c0 < C) ? (N - c0) : C;
            dim3 gr(HC / 128, (Cn + 127) / 128);
            gemm128<<<gr, 256, 0, stream>>>(x_bf + (size_t)c0 * K, xc + (size_t)c0 * K, flag,
                                            Wrt, xrc, Cn, HC, K);
            gat_aggregate<<<Cn, 256, 0, stream>>>(xl, HC, xrc, HC,
                                                  offsets, srcs, attc, biasc, Wcc, bcc,
                                                  out, c0, Cn, N, EN);
        }
    }
}